// Round 7
// baseline (1331.252 us; speedup 1.0000x reference)
//
#include <hip/hip_runtime.h>
#include <math.h>

#define NPTS 8192
#define NB 2
#define NROWS (NB * NPTS)
#define KNN 16

// Spatial grid: 32^3 cells of width H over [-4.8, 4.8] per axis.
// 4 grids: {P,T} x {batch0,batch1}. grid id g: P of batch b = 2b, T = 2b+1.
#define GRID 32
#define NCELLS (GRID * GRID * GRID)        // 32768
#define NGRIDS 4
#define TOTCELLS (NGRIDS * NCELLS)         // 131072
#define H 0.3f
#define RLO -4.8f
#define INVH (1.0f / H)
#define SCAN_BLOCKS 128                    // TOTCELLS / 1024

__device__ __forceinline__ int cellof(float x) {
  int c = (int)floorf((x - RLO) * INVH);
  return min(max(c, 0), GRID - 1);
}

__device__ __forceinline__ float sqd3(float qx, float qy, float qz, float4 c) {
  float dx = qx - c.x, dy = qy - c.y, dz = qz - c.z;
  return fmaf(dx, dx, fmaf(dy, dy, dz * dz));
}

// Guarded insert into ascending sorted-K list (exact; per-lane).
template <int K>
__device__ __forceinline__ void insertK(float (&a)[K], float d) {
  if (d < a[K - 1]) {
    a[K - 1] = d;
#pragma unroll
    for (int k = K - 1; k > 0; --k) {
      float lo = fminf(a[k - 1], a[k]);
      a[k] = fmaxf(a[k - 1], a[k]);
      a[k - 1] = lo;
    }
  }
}

template <int K>
__device__ __forceinline__ void visit_cell(
    int flat, const float4* __restrict__ sorted,
    const unsigned* __restrict__ counts, const unsigned* __restrict__ partial,
    const unsigned* __restrict__ aux, float qx, float qy, float qz,
    float (&a)[K]) {
  unsigned cnt = counts[flat];
  if (cnt == 0) return;
  unsigned start = partial[flat] + aux[flat >> 10];
  const float4* p = sorted + start;
  for (unsigned j = 0; j < cnt; ++j) {
    float4 c = p[j];
    insertK(a, sqd3(qx, qy, qz, c));
  }
}

// Exact kNN by expanding Chebyshev shells. After completing shell m, any
// unvisited point is at distance > m*H (per-axis cell gap >= m cells =>
// coordinate gap >= m*H; 0.999 slack covers float binning boundary error,
// which perturbs results by ~1e-6 << the 3.4e-3 output threshold).
// Clamping (of query cell or stored outlier points) only increases the true
// distance to unvisited cells, so the bound stays valid for outliers.
template <int K>
__device__ void grid_search(int g, float qx, float qy, float qz,
                            const float4* __restrict__ sorted,
                            const unsigned* __restrict__ counts,
                            const unsigned* __restrict__ partial,
                            const unsigned* __restrict__ aux, float (&a)[K]) {
  const int cx = cellof(qx), cy = cellof(qy), cz = cellof(qz);
  const int base = g * NCELLS;
  visit_cell(base + (cz * GRID + cy) * GRID + cx, sorted, counts, partial, aux,
             qx, qy, qz, a);
  for (int m = 1; m <= 48; ++m) {
    for (int dz = -m; dz <= m; ++dz) {
      int z = cz + dz;
      if (z < 0 || z >= GRID) continue;
      int adz = dz < 0 ? -dz : dz;
      int zb = base + z * GRID * GRID;
      for (int dy = -m; dy <= m; ++dy) {
        int y = cy + dy;
        if (y < 0 || y >= GRID) continue;
        int ady = dy < 0 ? -dy : dy;
        int yb = zb + y * GRID;
        if (adz == m || ady == m) {
          int xlo = max(cx - m, 0), xhi = min(cx + m, GRID - 1);
          for (int x = xlo; x <= xhi; ++x)
            visit_cell(yb + x, sorted, counts, partial, aux, qx, qy, qz, a);
        } else {
          int x = cx - m;
          if (x >= 0) visit_cell(yb + x, sorted, counts, partial, aux, qx, qy, qz, a);
          x = cx + m;
          if (x < GRID) visit_cell(yb + x, sorted, counts, partial, aux, qx, qy, qz, a);
        }
      }
    }
    float bb = (float)m * (H * 0.999f);
    if (a[K - 1] <= bb * bb) break;   // unvisited points are > m*H away
  }
}

__global__ __launch_bounds__(1024) void zero_kernel(unsigned* __restrict__ counts) {
  counts[blockIdx.x * 1024 + threadIdx.x] = 0u;
}

// Histogram points into cells. t < NROWS: pred point t; else true point t-NROWS.
__global__ __launch_bounds__(256) void count_kernel(
    const float* __restrict__ yp, const float* __restrict__ yt,
    unsigned* __restrict__ counts) {
  int t = blockIdx.x * 256 + threadIdx.x;          // 0 .. 2*NROWS-1
  const float* src;
  int g;
  if (t < NROWS) { src = yp + 3 * t; g = 2 * (t >> 13); }
  else { int u = t - NROWS; src = yt + 3 * u; g = 2 * (u >> 13) + 1; }
  int cx = cellof(src[0]), cy = cellof(src[1]), cz = cellof(src[2]);
  atomicAdd(&counts[g * NCELLS + (cz * GRID + cy) * GRID + cx], 1u);
}

// Block-level exclusive scan of counts (1024 cells/block); block sum -> aux.
// Also re-zeroes counts for reuse as the scatter cursor.
__global__ __launch_bounds__(1024) void scan1_kernel(
    unsigned* __restrict__ counts, unsigned* __restrict__ partial,
    unsigned* __restrict__ aux) {
  __shared__ unsigned s[1024];
  int t = threadIdx.x;
  int base = blockIdx.x * 1024;
  unsigned v = counts[base + t];
  s[t] = v;
  __syncthreads();
  for (int off = 1; off < 1024; off <<= 1) {
    unsigned add = (t >= off) ? s[t - off] : 0u;
    __syncthreads();
    s[t] += add;
    __syncthreads();
  }
  partial[base + t] = s[t] - v;          // exclusive within block
  if (t == 1023) aux[blockIdx.x] = s[t]; // block total
  counts[base + t] = 0u;                 // cursor for scatter
}

// Exclusive scan of the 128 block totals, in place.
__global__ __launch_bounds__(SCAN_BLOCKS) void scan2_kernel(unsigned* __restrict__ aux) {
  __shared__ unsigned s[SCAN_BLOCKS];
  int t = threadIdx.x;
  unsigned v = aux[t];
  s[t] = v;
  __syncthreads();
  for (int off = 1; off < SCAN_BLOCKS; off <<= 1) {
    unsigned add = (t >= off) ? s[t - off] : 0u;
    __syncthreads();
    s[t] += add;
    __syncthreads();
  }
  aux[t] = s[t] - v;
}

// Counting-sort scatter: sorted[pos] = (x,y,z, bits(original row)).
__global__ __launch_bounds__(256) void scatter_kernel(
    const float* __restrict__ yp, const float* __restrict__ yt,
    unsigned* __restrict__ counts, const unsigned* __restrict__ partial,
    const unsigned* __restrict__ aux, float4* __restrict__ sorted) {
  int t = blockIdx.x * 256 + threadIdx.x;
  const float* src;
  int g, row;
  if (t < NROWS) { row = t; src = yp + 3 * t; g = 2 * (t >> 13); }
  else { row = t - NROWS; src = yt + 3 * row; g = 2 * (row >> 13) + 1; }
  float x = src[0], y = src[1], z = src[2];
  int flat = g * NCELLS + (cellof(z) * GRID + cellof(y)) * GRID + cellof(x);
  unsigned pos = partial[flat] + aux[flat >> 10] + atomicAdd(&counts[flat], 1u);
  sorted[pos] = make_float4(x, y, z, __int_as_float(row));
}

// One lane per query, spatially-coherent order (lanes iterate sorted entries).
// blocks [0,256): kNN of true point vs P-grid -> minrow + knnP distances
// blocks [256,512): kNN of true point vs T-grid -> knnT distances (self incl.)
// blocks [512,768): NN of pred point vs T-grid -> mincol
__global__ __launch_bounds__(64) void query_kernel(
    const float4* __restrict__ sorted, const unsigned* __restrict__ counts,
    const unsigned* __restrict__ partial, const unsigned* __restrict__ aux,
    float* __restrict__ knnP, float* __restrict__ knnT,
    float* __restrict__ minrow_arr, float* __restrict__ mincol_arr) {
  const int type = blockIdx.x >> 8;                       // 0,1,2
  const int qid = (blockIdx.x & 255) * 64 + threadIdx.x;  // 0 .. 16383
  const int b = qid >> 13;
  const int src_g = (type == 2) ? 2 * b : 2 * b + 1;      // P entries for type2
  float4 e = sorted[src_g * NPTS + (qid & (NPTS - 1))];
  const int row = __float_as_int(e.w);
  if (type < 2) {
    const int tgt_g = (type == 0) ? 2 * b : 2 * b + 1;
    float a[KNN];
#pragma unroll
    for (int k = 0; k < KNN; ++k) a[k] = INFINITY;
    grid_search(tgt_g, e.x, e.y, e.z, sorted, counts, partial, aux, a);
    if (type == 0) {
      minrow_arr[row] = sqrtf(a[0]);
#pragma unroll
      for (int k = 0; k < KNN; ++k) knnP[row * KNN + k] = sqrtf(a[k]);
    } else {
#pragma unroll
      for (int k = 0; k < KNN; ++k) knnT[row * KNN + k] = sqrtf(a[k]);
    }
  } else {
    float a[1] = {INFINITY};
    grid_search(2 * b + 1, e.x, e.y, e.z, sorted, counts, partial, aux, a);
    mincol_arr[row] = sqrtf(a[0]);
  }
}

// Per-row positional |knnP - knnT| sum.
__global__ __launch_bounds__(256) void combine_kernel(
    const float* __restrict__ knnP, const float* __restrict__ knnT,
    float* __restrict__ density_arr) {
  int row = blockIdx.x * 256 + threadIdx.x;
  float s = 0.0f;
#pragma unroll
  for (int k = 0; k < KNN; ++k)
    s += fabsf(knnP[row * KNN + k] - knnT[row * KNN + k]);
  density_arr[row] = s;
}

// Deterministic single-block reduction -> 3 outputs.
__global__ __launch_bounds__(256) void finalize_kernel(
    const float* __restrict__ minrow_arr, const float* __restrict__ mincol_arr,
    const float* __restrict__ density_arr, float* __restrict__ out) {
  __shared__ double s1[256], s2[256], s3[256];
  const int t = threadIdx.x;
  double a = 0.0, b = 0.0, c = 0.0;
  for (int idx = t; idx < NROWS; idx += 256) {
    a += (double)minrow_arr[idx];
    b += (double)mincol_arr[idx];
    c += (double)density_arr[idx];
  }
  s1[t] = a; s2[t] = b; s3[t] = c;
  __syncthreads();
  for (int off = 128; off > 0; off >>= 1) {
    if (t < off) { s1[t] += s1[t + off]; s2[t] += s2[t + off]; s3[t] += s3[t + off]; }
    __syncthreads();
  }
  if (t == 0) {
    double shape = 0.5 * (s1[0] + s2[0]) / (double)NROWS;
    double dens = s3[0] / ((double)NROWS * KNN);
    out[0] = (float)(shape + dens);  // data_loss
    out[1] = (float)shape;           // shape_loss
    out[2] = (float)dens;            // density_loss
  }
}

extern "C" void kernel_launch(void* const* d_in, const int* in_sizes, int n_in,
                              void* d_out, int out_size, void* d_ws, size_t ws_size,
                              hipStream_t stream) {
  (void)in_sizes; (void)n_in; (void)out_size; (void)ws_size;
  const float* yp = (const float*)d_in[0];  // y_pred [B, N, 3]
  const float* yt = (const float*)d_in[1];  // y_true [B, N, 3]
  char* ws = (char*)d_ws;
  unsigned* counts  = (unsigned*)ws;                       ws += TOTCELLS * 4;  // 512 KB
  unsigned* partial = (unsigned*)ws;                       ws += TOTCELLS * 4;  // 512 KB
  unsigned* aux     = (unsigned*)ws;                       ws += 256 * 4;
  float4*   sorted  = (float4*)ws;                         ws += 2 * NROWS * 16; // 512 KB
  float*    knnP    = (float*)ws;                          ws += NROWS * KNN * 4; // 1 MB
  float*    knnT    = (float*)ws;                          ws += NROWS * KNN * 4; // 1 MB
  float*    minrow_arr  = (float*)ws;                      ws += NROWS * 4;
  float*    mincol_arr  = (float*)ws;                      ws += NROWS * 4;
  float*    density_arr = (float*)ws;                      ws += NROWS * 4;
  float* out = (float*)d_out;

  zero_kernel<<<TOTCELLS / 1024, 1024, 0, stream>>>(counts);
  count_kernel<<<2 * NROWS / 256, 256, 0, stream>>>(yp, yt, counts);
  scan1_kernel<<<SCAN_BLOCKS, 1024, 0, stream>>>(counts, partial, aux);
  scan2_kernel<<<1, SCAN_BLOCKS, 0, stream>>>(aux);
  scatter_kernel<<<2 * NROWS / 256, 256, 0, stream>>>(yp, yt, counts, partial, aux, sorted);
  query_kernel<<<768, 64, 0, stream>>>(sorted, counts, partial, aux,
                                       knnP, knnT, minrow_arr, mincol_arr);
  combine_kernel<<<NROWS / 256, 256, 0, stream>>>(knnP, knnT, density_arr);
  finalize_kernel<<<1, 256, 0, stream>>>(minrow_arr, mincol_arr, density_arr, out);
}

// Round 8
// 190.859 us; speedup vs baseline: 6.9750x; 6.9750x over previous
//
#include <hip/hip_runtime.h>
#include <math.h>

#define NPTS 8192
#define NB 2
#define NROWS (NB * NPTS)
#define KNN 16

// Spatial grid: 32^3 cells of width H. 4 grids: P/T x batch. g: P=2b, T=2b+1.
#define GRID 32
#define NCELLS (GRID * GRID * GRID)        // 32768
#define TOTCELLS (4 * NCELLS)              // 131072
#define H 0.35f
#define RLO (-5.6f)
#define INVH (1.0f / H)
#define SCAN_BLOCKS 128
#define SEGCAP 132                          // >= 2*64 segments per row-chunk

__device__ __forceinline__ int cellof(float x) {
  int c = (int)floorf((x - RLO) * INVH);
  return min(max(c, 0), GRID - 1);
}

__device__ __forceinline__ float sqd3(float qx, float qy, float qz, float4 c) {
  float dx = qx - c.x, dy = qy - c.y, dz = qz - c.z;
  return fmaf(dx, dx, fmaf(dy, dy, dz * dz));
}

__device__ __forceinline__ int lanerank(unsigned long long mk) {
  return __builtin_amdgcn_mbcnt_hi((unsigned)(mk >> 32),
                                   __builtin_amdgcn_mbcnt_lo((unsigned)mk, 0));
}

// Guarded insert into ascending sorted-K list (exact; per-lane).
template <int K>
__device__ __forceinline__ void insertK(float (&a)[K], float d) {
  if (d < a[K - 1]) {
    a[K - 1] = d;
#pragma unroll
    for (int k = K - 1; k > 0; --k) {
      float lo = fminf(a[k - 1], a[k]);
      a[k] = fmaxf(a[k - 1], a[k]);
      a[k - 1] = lo;
    }
  }
}

// Wave-cooperative exact kNN via expanding Chebyshev shells on a counting-
// sorted grid. Correctness: after completing shell m, any unvisited point is
// at distance > m*H (per-axis cell gap; 0.999 slack covers float binning
// boundary error ~1e-7 << 3.4e-3 output threshold; clamped cells only
// increase true distances, so outliers are safe). Stop when the wave has
// seen >= K candidates within the bound -- the per-lane sorted lists then
// provably contain the global top-K (discards are always >= the lane's
// current a[K-1] >= final a[K-1]).
template <int K>
__device__ void wave_grid_knn(int g, float qx, float qy, float qz,
                              const float4* __restrict__ sorted,
                              const unsigned* __restrict__ pack,
                              unsigned* sStart, unsigned* sCnt, unsigned* sPre,
                              int lane, float (&a)[K]) {
  const int cx = cellof(qx), cy = cellof(qy), cz = cellof(qz);
  const int base = g * NCELLS;
  for (int m = 0; m <= 34; ++m) {
    const int zlo = max(cz - m, 0), zhi = min(cz + m, GRID - 1);
    const int ylo = max(cy - m, 0), yhi = min(cy + m, GRID - 1);
    const int xlo = max(cx - m, 0), xhi = min(cx + m, GRID - 1);
    const int ny = yhi - ylo + 1;
    const int nrows = (zhi - zlo + 1) * ny;
    for (int rb = 0; rb < nrows; rb += 64) {
      const int rho = rb + lane;
      const bool act = rho < nrows;
      const int rr = act ? rho : 0;
      const int z = zlo + rr / ny, y = ylo + rr % ny;
      const int dza = abs(z - cz), dya = abs(y - cy);
      const bool bdry = (dza == m) || (dya == m);
      unsigned stA = 0, cnA = 0, stB = 0, cnB = 0;
      const int rowbase = base + (z * GRID + y) * GRID;
      if (act) {
        if (bdry) {  // full (clamped) x-range: contiguous segment, 2 loads
          unsigned plo = pack[rowbase + xlo];
          unsigned phi = pack[rowbase + xhi];
          stA = plo >> 14;
          cnA = ((phi >> 14) + (phi & 16383u)) - stA;
        } else {     // interior row: only the two new x = cx +- m cells
          int xl = cx - m, xr = cx + m;
          if (xl >= 0) { unsigned p = pack[rowbase + xl]; stA = p >> 14; cnA = p & 16383u; }
          if (xr < GRID) { unsigned p = pack[rowbase + xr]; stB = p >> 14; cnB = p & 16383u; }
        }
      }
      // ballot-compact nonempty segments into wave-private LDS
      unsigned long long mA = __ballot(cnA > 0);
      unsigned long long mB = __ballot(cnB > 0);
      int nA = __popcll(mA);
      int nseg = nA + __popcll(mB);
      if (nseg == 0) continue;
      int slA = lanerank(mA), slB = nA + lanerank(mB);
      if (cnA > 0) { sStart[slA] = stA; sCnt[slA] = cnA; }
      if (cnB > 0) { sStart[slB] = stB; sCnt[slB] = cnB; }
      // exclusive prefix over segment counts (<=128 segs, 2 halves of 64)
      unsigned total = 0;
      for (int h = 0; h < 2; ++h) {
        int sl = h * 64 + lane;
        unsigned v = (sl < nseg) ? sCnt[sl] : 0u;
        unsigned inc = v;
#pragma unroll
        for (int s2 = 1; s2 < 64; s2 <<= 1) {
          unsigned t = __shfl_up(inc, s2, 64);
          if (lane >= s2) inc += t;
        }
        if (sl < nseg) sPre[sl] = total + inc - v;
        total += __shfl(inc, 63, 64);
        if (nseg <= 64) break;
      }
      // candidates 64-wide across segment boundaries
      for (unsigned cb = 0; cb < total; cb += 64) {
        unsigned c = cb + (unsigned)lane;
        bool cact = c < total;
        unsigned cc = cact ? c : (total - 1);
        int lo = 0;  // max seg with sPre[seg] <= cc (sPre[0]==0)
#pragma unroll
        for (int sh = 64; sh >= 1; sh >>= 1) {
          int mid = lo + sh;
          if (mid < nseg && sPre[mid] <= cc) lo = mid;
        }
        float4 p = sorted[sStart[lo] + (cc - sPre[lo])];
        float d = cact ? sqd3(qx, qy, qz, p) : INFINITY;
        insertK(a, d);
      }
    }
    // stop test: >= K candidates within the provable bound?
    float bb = (float)m * (H * 0.999f);
    float bb2 = bb * bb;
    int cnt = 0;
#pragma unroll
    for (int k = 0; k < K; ++k) cnt += (a[k] <= bb2) ? 1 : 0;
#pragma unroll
    for (int s2 = 1; s2 < 64; s2 <<= 1) cnt += __shfl_xor(cnt, s2, 64);
    bool covered = (zlo == 0 && zhi == GRID - 1 && ylo == 0 &&
                    yhi == GRID - 1 && xlo == 0 && xhi == GRID - 1);
    if (cnt >= K || covered) break;
  }
}

// Extract wave-global ascending top-16 from per-lane sorted a[16]:
// lane r (r<16) returns the r-th smallest.
__device__ __forceinline__ float wave_extract16(float (&a)[KNN], int lane) {
  float res = INFINITY;
#pragma unroll 1
  for (int r = 0; r < KNN; ++r) {
    float v = a[0];
    int idx = lane;
#pragma unroll
    for (int s = 1; s < 64; s <<= 1) {
      float ov = __shfl_xor(v, s, 64);
      int oi = __shfl_xor(idx, s, 64);
      bool take = (ov < v) || (ov == v && oi < idx);
      v = take ? ov : v;
      idx = take ? oi : idx;
    }
    if (lane == r) res = v;
    if (lane == idx) {
#pragma unroll
      for (int k = 0; k < KNN - 1; ++k) a[k] = a[k + 1];
      a[KNN - 1] = INFINITY;
    }
  }
  return res;
}

// ---------- build ----------
__global__ __launch_bounds__(256) void count_kernel(
    const float* __restrict__ yp, const float* __restrict__ yt,
    unsigned* __restrict__ counts) {
  int t = blockIdx.x * 256 + threadIdx.x;          // 0 .. 2*NROWS-1
  const float* src;
  int g;
  if (t < NROWS) { src = yp + 3 * t; g = 2 * (t >> 13); }
  else { int u = t - NROWS; src = yt + 3 * u; g = 2 * (u >> 13) + 1; }
  atomicAdd(&counts[g * NCELLS + (cellof(src[2]) * GRID + cellof(src[1])) * GRID + cellof(src[0])], 1u);
}

__global__ __launch_bounds__(1024) void scan1_kernel(
    const unsigned* __restrict__ counts, unsigned* __restrict__ partial,
    unsigned* __restrict__ aux) {
  __shared__ unsigned s[1024];
  int t = threadIdx.x;
  int base = blockIdx.x * 1024;
  unsigned v = counts[base + t];
  s[t] = v;
  __syncthreads();
  for (int off = 1; off < 1024; off <<= 1) {
    unsigned add = (t >= off) ? s[t - off] : 0u;
    __syncthreads();
    s[t] += add;
    __syncthreads();
  }
  partial[base + t] = s[t] - v;
  if (t == 1023) aux[blockIdx.x] = s[t];
}

__global__ __launch_bounds__(SCAN_BLOCKS) void scan2_kernel(unsigned* __restrict__ aux) {
  __shared__ unsigned s[SCAN_BLOCKS];
  int t = threadIdx.x;
  unsigned v = aux[t];
  s[t] = v;
  __syncthreads();
  for (int off = 1; off < SCAN_BLOCKS; off <<= 1) {
    unsigned add = (t >= off) ? s[t - off] : 0u;
    __syncthreads();
    s[t] += add;
    __syncthreads();
  }
  aux[t] = s[t] - v;
}

// cellinfo pack: global start (17b) << 14 | count (14b)
__global__ __launch_bounds__(1024) void pack_kernel(
    const unsigned* __restrict__ counts, const unsigned* __restrict__ partial,
    const unsigned* __restrict__ aux, unsigned* __restrict__ pack) {
  int i = blockIdx.x * 1024 + threadIdx.x;
  unsigned start = partial[i] + aux[i >> 10];
  pack[i] = (start << 14) | counts[i];
}

__global__ __launch_bounds__(256) void scatter_kernel(
    const float* __restrict__ yp, const float* __restrict__ yt,
    const unsigned* __restrict__ pack, unsigned* __restrict__ cursor,
    float4* __restrict__ sorted) {
  int t = blockIdx.x * 256 + threadIdx.x;
  const float* src;
  int g, row;
  if (t < NROWS) { row = t; src = yp + 3 * t; g = 2 * (t >> 13); }
  else { row = t - NROWS; src = yt + 3 * row; g = 2 * (row >> 13) + 1; }
  float x = src[0], y = src[1], z = src[2];
  int flat = g * NCELLS + (cellof(z) * GRID + cellof(y)) * GRID + cellof(x);
  unsigned pos = (pack[flat] >> 14) + atomicAdd(&cursor[flat], 1u);
  sorted[pos] = make_float4(x, y, z, __int_as_float(row));
}

// ---------- queries: one wave per query, spatially-sorted order ----------
// wid [0,16384): T point vs P grid  -> knnP row (16 sqrt'd dists)
// wid [16384,32768): T vs T grid    -> knnT row (self included)
// wid [32768,49152): P vs T grid    -> mincol
__global__ __launch_bounds__(256) void query_kernel(
    const float4* __restrict__ sorted, const unsigned* __restrict__ pack,
    float* __restrict__ knnP, float* __restrict__ knnT,
    float* __restrict__ mincol_arr) {
  __shared__ unsigned sb[4][3][SEGCAP];
  const int wave = threadIdx.x >> 6, lane = threadIdx.x & 63;
  const int wid = blockIdx.x * 4 + wave;
  const int type = wid >> 14;
  const int qid = wid & 16383;
  const int b = qid >> 13;
  const int src_g = (type == 2) ? 2 * b : 2 * b + 1;
  float4 e = sorted[src_g * NPTS + (qid & (NPTS - 1))];
  const int row = __float_as_int(e.w);
  unsigned* sS = sb[wave][0];
  unsigned* sC = sb[wave][1];
  unsigned* sP = sb[wave][2];
  if (type < 2) {
    const int tgt_g = (type == 0) ? 2 * b : 2 * b + 1;
    float a[KNN];
#pragma unroll
    for (int k = 0; k < KNN; ++k) a[k] = INFINITY;
    wave_grid_knn<KNN>(tgt_g, e.x, e.y, e.z, sorted, pack, sS, sC, sP, lane, a);
    float res = wave_extract16(a, lane);
    float* dst = (type == 0) ? knnP : knnT;
    if (lane < KNN) dst[row * KNN + lane] = sqrtf(res);
  } else {
    float a1[1] = {INFINITY};
    wave_grid_knn<1>(2 * b + 1, e.x, e.y, e.z, sorted, pack, sS, sC, sP, lane, a1);
    float v = a1[0];
#pragma unroll
    for (int s = 1; s < 64; s <<= 1) v = fminf(v, __shfl_xor(v, s, 64));
    if (lane == 0) mincol_arr[row] = sqrtf(v);
  }
}

// Per-block deterministic double partials: minrow (=knnP[.][0]), mincol, density.
__global__ __launch_bounds__(256) void combine_kernel(
    const float* __restrict__ knnP, const float* __restrict__ knnT,
    const float* __restrict__ mincol_arr, double* __restrict__ pd) {
  __shared__ double s1[256], s2[256], s3[256];
  const int t = threadIdx.x;
  const int row = blockIdx.x * 256 + t;
  float s = 0.0f;
#pragma unroll
  for (int k = 0; k < KNN; ++k)
    s += fabsf(knnP[row * KNN + k] - knnT[row * KNN + k]);
  s1[t] = (double)knnP[row * KNN];
  s2[t] = (double)mincol_arr[row];
  s3[t] = (double)s;
  __syncthreads();
  for (int off = 128; off > 0; off >>= 1) {
    if (t < off) { s1[t] += s1[t + off]; s2[t] += s2[t + off]; s3[t] += s3[t + off]; }
    __syncthreads();
  }
  if (t == 0) {
    pd[blockIdx.x * 3 + 0] = s1[0];
    pd[blockIdx.x * 3 + 1] = s2[0];
    pd[blockIdx.x * 3 + 2] = s3[0];
  }
}

__global__ __launch_bounds__(64) void finalize_kernel(
    const double* __restrict__ pd, float* __restrict__ out) {
  const int t = threadIdx.x;
  double a = pd[t * 3], b = pd[t * 3 + 1], c = pd[t * 3 + 2];
#pragma unroll
  for (int s = 32; s >= 1; s >>= 1) {
    a += __shfl_down(a, s, 64);
    b += __shfl_down(b, s, 64);
    c += __shfl_down(c, s, 64);
  }
  if (t == 0) {
    double shape = 0.5 * (a + b) / (double)NROWS;
    double dens = c / ((double)NROWS * KNN);
    out[0] = (float)(shape + dens);
    out[1] = (float)shape;
    out[2] = (float)dens;
  }
}

extern "C" void kernel_launch(void* const* d_in, const int* in_sizes, int n_in,
                              void* d_out, int out_size, void* d_ws, size_t ws_size,
                              hipStream_t stream) {
  (void)in_sizes; (void)n_in; (void)out_size; (void)ws_size;
  const float* yp = (const float*)d_in[0];  // y_pred [B, N, 3]
  const float* yt = (const float*)d_in[1];  // y_true [B, N, 3]
  char* w = (char*)d_ws;
  unsigned* counts  = (unsigned*)w;  w += TOTCELLS * 4;     // 512 KB
  unsigned* cursor  = (unsigned*)w;  w += TOTCELLS * 4;     // 512 KB (contig w/ counts)
  unsigned* partial = (unsigned*)w;  w += TOTCELLS * 4;
  unsigned* aux     = (unsigned*)w;  w += 512;
  unsigned* pack    = (unsigned*)w;  w += TOTCELLS * 4;
  float4*   sorted  = (float4*)w;    w += 2 * NROWS * 16;   // 1 MB
  float*    knnP    = (float*)w;     w += NROWS * KNN * 4;  // 1 MB
  float*    knnT    = (float*)w;     w += NROWS * KNN * 4;  // 1 MB
  float*    mincol  = (float*)w;     w += NROWS * 4;
  double*   pd      = (double*)w;    w += 64 * 3 * 8;
  float* out = (float*)d_out;

  hipMemsetAsync(counts, 0, 2 * (size_t)TOTCELLS * 4, stream);  // counts+cursor
  count_kernel<<<2 * NROWS / 256, 256, 0, stream>>>(yp, yt, counts);
  scan1_kernel<<<SCAN_BLOCKS, 1024, 0, stream>>>(counts, partial, aux);
  scan2_kernel<<<1, SCAN_BLOCKS, 0, stream>>>(aux);
  pack_kernel<<<TOTCELLS / 1024, 1024, 0, stream>>>(counts, partial, aux, pack);
  scatter_kernel<<<2 * NROWS / 256, 256, 0, stream>>>(yp, yt, pack, cursor, sorted);
  query_kernel<<<3 * 16384 / 4, 256, 0, stream>>>(sorted, pack, knnP, knnT, mincol);
  combine_kernel<<<NROWS / 256, 256, 0, stream>>>(knnP, knnT, mincol, pd);
  finalize_kernel<<<1, 64, 0, stream>>>(pd, out);
}

// Round 9
// 181.021 us; speedup vs baseline: 7.3541x; 1.0543x over previous
//
#include <hip/hip_runtime.h>
#include <math.h>

#define NPTS 8192
#define NB 2
#define NROWS (NB * NPTS)
#define KNN 16
#define KC 4          // per-lane kept candidates (truncated sorted list)

// Spatial grid: 32^3 cells of width H. 4 grids: P/T x batch. g: P=2b, T=2b+1.
#define GRID 32
#define NCELLS (GRID * GRID * GRID)        // 32768
#define TOTCELLS (4 * NCELLS)              // 131072
#define H 0.35f
#define RLO (-5.6f)
#define INVH (1.0f / H)
#define SCAN_BLOCKS 128
#define SEGCAP 132                          // >= 2*64 segments per row-chunk

__device__ __forceinline__ int cellof(float x) {
  int c = (int)floorf((x - RLO) * INVH);
  return min(max(c, 0), GRID - 1);
}

__device__ __forceinline__ float sqd3(float qx, float qy, float qz, float4 c) {
  float dx = qx - c.x, dy = qy - c.y, dz = qz - c.z;
  return fmaf(dx, dx, fmaf(dy, dy, dz * dz));
}

__device__ __forceinline__ int lanerank(unsigned long long mk) {
  return __builtin_amdgcn_mbcnt_hi((unsigned)(mk >> 32),
                                   __builtin_amdgcn_mbcnt_lo((unsigned)mk, 0));
}

// Guarded insert into ascending sorted-K list (per-lane).
template <int K>
__device__ __forceinline__ void insertK(float (&a)[K], float d) {
  if (d < a[K - 1]) {
    a[K - 1] = d;
#pragma unroll
    for (int k = K - 1; k > 0; --k) {
      float lo = fminf(a[k - 1], a[k]);
      a[k] = fmaxf(a[k - 1], a[k]);
      a[k - 1] = lo;
    }
  }
}

// Full ascending bitonic sort of one value per lane across the 64-lane wave.
__device__ __forceinline__ float bitonic_sort64(float v, int lane) {
#pragma unroll
  for (int k = 2; k <= 64; k <<= 1) {
#pragma unroll
    for (int j = k >> 1; j >= 1; j >>= 1) {
      float o = __shfl_xor(v, j, 64);
      bool up = ((lane & k) == 0);
      bool lower = ((lane & j) == 0);
      float mn = fminf(v, o), mx = fmaxf(v, o);
      v = (up == lower) ? mn : mx;
    }
  }
  return v;
}

// Wave-cooperative kNN via expanding Chebyshev shells on a counting-sorted
// grid. After completing shell m, any unvisited point is at distance > m*H
// (0.999 slack covers float binning boundary error ~1e-7 << 3.4e-3 output
// threshold; clamped cells only increase true distances). Per-lane lists are
// truncated to K kept values; `ovf` records that a lane processed a real
// candidate while its list was full (=> some real value was discarded, and
// every discard >= the lane's final a[K-1], since a[K-1] is non-increasing).
// Stop when the wave has seen >= NEED candidates within the bound (counted
// from kept values only -- an undercount, so stopping is conservative).
template <int K, int NEED>
__device__ void wave_grid_knn(int g, float qx, float qy, float qz,
                              const float4* __restrict__ sorted,
                              const unsigned* __restrict__ pack,
                              unsigned* sStart, unsigned* sCnt, unsigned* sPre,
                              int lane, float (&a)[K], bool& ovf) {
  const int cx = cellof(qx), cy = cellof(qy), cz = cellof(qz);
  const int base = g * NCELLS;
  for (int m = 0; m <= 34; ++m) {
    const int zlo = max(cz - m, 0), zhi = min(cz + m, GRID - 1);
    const int ylo = max(cy - m, 0), yhi = min(cy + m, GRID - 1);
    const int xlo = max(cx - m, 0), xhi = min(cx + m, GRID - 1);
    const int ny = yhi - ylo + 1;
    const int nrows = (zhi - zlo + 1) * ny;
    for (int rb = 0; rb < nrows; rb += 64) {
      const int rho = rb + lane;
      const bool act = rho < nrows;
      const int rr = act ? rho : 0;
      const int z = zlo + rr / ny, y = ylo + rr % ny;
      const int dza = abs(z - cz), dya = abs(y - cy);
      const bool bdry = (dza == m) || (dya == m);
      unsigned stA = 0, cnA = 0, stB = 0, cnB = 0;
      const int rowbase = base + (z * GRID + y) * GRID;
      if (act) {
        if (bdry) {  // full (clamped) x-range: contiguous segment, 2 loads
          unsigned plo = pack[rowbase + xlo];
          unsigned phi = pack[rowbase + xhi];
          stA = plo >> 14;
          cnA = ((phi >> 14) + (phi & 16383u)) - stA;
        } else {     // interior row: only the two new x = cx +- m cells
          int xl = cx - m, xr = cx + m;
          if (xl >= 0) { unsigned p = pack[rowbase + xl]; stA = p >> 14; cnA = p & 16383u; }
          if (xr < GRID) { unsigned p = pack[rowbase + xr]; stB = p >> 14; cnB = p & 16383u; }
        }
      }
      // ballot-compact nonempty segments into wave-private LDS
      unsigned long long mA = __ballot(cnA > 0);
      unsigned long long mB = __ballot(cnB > 0);
      int nA = __popcll(mA);
      int nseg = nA + __popcll(mB);
      if (nseg == 0) continue;
      int slA = lanerank(mA), slB = nA + lanerank(mB);
      if (cnA > 0) { sStart[slA] = stA; sCnt[slA] = cnA; }
      if (cnB > 0) { sStart[slB] = stB; sCnt[slB] = cnB; }
      // exclusive prefix over segment counts (<=128 segs, 2 halves of 64)
      unsigned total = 0;
      for (int h = 0; h < 2; ++h) {
        int sl = h * 64 + lane;
        unsigned v = (sl < nseg) ? sCnt[sl] : 0u;
        unsigned inc = v;
#pragma unroll
        for (int s2 = 1; s2 < 64; s2 <<= 1) {
          unsigned t = __shfl_up(inc, s2, 64);
          if (lane >= s2) inc += t;
        }
        if (sl < nseg) sPre[sl] = total + inc - v;
        total += __shfl(inc, 63, 64);
        if (nseg <= 64) break;
      }
      // candidates 64-wide across segment boundaries
      for (unsigned cb = 0; cb < total; cb += 64) {
        unsigned c = cb + (unsigned)lane;
        bool cact = c < total;
        unsigned cc = cact ? c : (total - 1);
        int lo = 0;  // max seg with sPre[seg] <= cc (sPre[0]==0)
#pragma unroll
        for (int sh = 64; sh >= 1; sh >>= 1) {
          int mid = lo + sh;
          if (mid < nseg && sPre[mid] <= cc) lo = mid;
        }
        float4 p = sorted[sStart[lo] + (cc - sPre[lo])];
        float d = cact ? sqd3(qx, qy, qz, p) : INFINITY;
        ovf = ovf || (cact && a[K - 1] < INFINITY);  // full => a discard occurs
        insertK(a, d);
      }
    }
    // stop test: >= NEED candidates within the provable bound?
    float bb = (float)m * (H * 0.999f);
    float bb2 = bb * bb;
    int cnt = 0;
#pragma unroll
    for (int k = 0; k < K; ++k) cnt += (a[k] <= bb2) ? 1 : 0;
#pragma unroll
    for (int s2 = 1; s2 < 64; s2 <<= 1) cnt += __shfl_xor(cnt, s2, 64);
    bool covered = (zlo == 0 && zhi == GRID - 1 && ylo == 0 &&
                    yhi == GRID - 1 && xlo == 0 && xhi == GRID - 1);
    if (cnt >= NEED || covered) break;
  }
}

// ---------- build ----------
__global__ __launch_bounds__(256) void count_kernel(
    const float* __restrict__ yp, const float* __restrict__ yt,
    unsigned* __restrict__ counts) {
  int t = blockIdx.x * 256 + threadIdx.x;          // 0 .. 2*NROWS-1
  const float* src;
  int g;
  if (t < NROWS) { src = yp + 3 * t; g = 2 * (t >> 13); }
  else { int u = t - NROWS; src = yt + 3 * u; g = 2 * (u >> 13) + 1; }
  atomicAdd(&counts[g * NCELLS + (cellof(src[2]) * GRID + cellof(src[1])) * GRID + cellof(src[0])], 1u);
}

__global__ __launch_bounds__(1024) void scan1_kernel(
    const unsigned* __restrict__ counts, unsigned* __restrict__ partial,
    unsigned* __restrict__ aux) {
  __shared__ unsigned s[1024];
  int t = threadIdx.x;
  int base = blockIdx.x * 1024;
  unsigned v = counts[base + t];
  s[t] = v;
  __syncthreads();
  for (int off = 1; off < 1024; off <<= 1) {
    unsigned add = (t >= off) ? s[t - off] : 0u;
    __syncthreads();
    s[t] += add;
    __syncthreads();
  }
  partial[base + t] = s[t] - v;
  if (t == 1023) aux[blockIdx.x] = s[t];
}

__global__ __launch_bounds__(SCAN_BLOCKS) void scan2_kernel(unsigned* __restrict__ aux) {
  __shared__ unsigned s[SCAN_BLOCKS];
  int t = threadIdx.x;
  unsigned v = aux[t];
  s[t] = v;
  __syncthreads();
  for (int off = 1; off < SCAN_BLOCKS; off <<= 1) {
    unsigned add = (t >= off) ? s[t - off] : 0u;
    __syncthreads();
    s[t] += add;
    __syncthreads();
  }
  aux[t] = s[t] - v;
}

// cellinfo pack: global start (<=18b) << 14 | count (14b)
__global__ __launch_bounds__(1024) void pack_kernel(
    const unsigned* __restrict__ counts, const unsigned* __restrict__ partial,
    const unsigned* __restrict__ aux, unsigned* __restrict__ pack) {
  int i = blockIdx.x * 1024 + threadIdx.x;
  unsigned start = partial[i] + aux[i >> 10];
  pack[i] = (start << 14) | counts[i];
}

__global__ __launch_bounds__(256) void scatter_kernel(
    const float* __restrict__ yp, const float* __restrict__ yt,
    const unsigned* __restrict__ pack, unsigned* __restrict__ cursor,
    float4* __restrict__ sorted) {
  int t = blockIdx.x * 256 + threadIdx.x;
  const float* src;
  int g, row;
  if (t < NROWS) { row = t; src = yp + 3 * t; g = 2 * (t >> 13); }
  else { row = t - NROWS; src = yt + 3 * row; g = 2 * (row >> 13) + 1; }
  float x = src[0], y = src[1], z = src[2];
  int flat = g * NCELLS + (cellof(z) * GRID + cellof(y)) * GRID + cellof(x);
  unsigned pos = (pack[flat] >> 14) + atomicAdd(&cursor[flat], 1u);
  sorted[pos] = make_float4(x, y, z, __int_as_float(row));
}

// ---------- queries: one wave per query, spatially-sorted order ----------
// wid [0,16384): T point vs P grid  -> knnP row (16 sqrt'd dists) + flag
// wid [16384,32768): T vs T grid    -> knnT row (self included) + flag
// wid [32768,49152): P vs T grid    -> mincol (exact, no flag)
__global__ __launch_bounds__(256) void query_kernel(
    const float4* __restrict__ sorted, const unsigned* __restrict__ pack,
    float* __restrict__ knnP, float* __restrict__ knnT,
    float* __restrict__ mincol_arr, unsigned* __restrict__ flags) {
  __shared__ unsigned sb[4][3][SEGCAP];
  __shared__ float cb[4][64];
  const int wave = threadIdx.x >> 6, lane = threadIdx.x & 63;
  const int wid = blockIdx.x * 4 + wave;
  const int type = wid >> 14;
  const int qid = wid & 16383;
  const int b = qid >> 13;
  const int src_g = (type == 2) ? 2 * b : 2 * b + 1;
  float4 e = sorted[src_g * NPTS + (qid & (NPTS - 1))];
  const int row = __float_as_int(e.w);
  unsigned* sS = sb[wave][0];
  unsigned* sC = sb[wave][1];
  unsigned* sP = sb[wave][2];
  float* cbuf = cb[wave];
  if (type < 2) {
    const int tgt_g = (type == 0) ? 2 * b : 2 * b + 1;
    float a[KC];
#pragma unroll
    for (int k = 0; k < KC; ++k) a[k] = INFINITY;
    bool ovf = false;
    wave_grid_knn<KC, KNN>(tgt_g, e.x, e.y, e.z, sorted, pack, sS, sC, sP,
                           lane, a, ovf);
    // tau = 16th-smallest lane-min: >= 16 distinct candidates <= tau
    // (lane minima are never truncated away).
    float slm = bitonic_sort64(a[0], lane);
    float tau = __shfl(slm, 15, 64);
    // compact all kept values <= tau, sort -> exact ascending top-16
    int tot = 0;
    int idx[KC];
#pragma unroll
    for (int k = 0; k < KC; ++k) {
      unsigned long long mk = __ballot(a[k] <= tau);
      idx[k] = tot + lanerank(mk);
      tot += __popcll(mk);
    }
#pragma unroll
    for (int k = 0; k < KC; ++k)
      if (a[k] <= tau && idx[k] < 64) cbuf[idx[k]] = a[k];
    float v = (lane < tot) ? cbuf[lane] : INFINITY;  // same-wave: no barrier
    v = bitonic_sort64(v, lane);
    float f15 = __shfl(v, 15, 64);
    // exact unless compact overflowed or some lane may have discarded a
    // value <= f15 (all discards >= that lane's final a[KC-1]).
    bool lanebad = ovf && (a[KC - 1] <= f15);
    bool bad = (tot > 64) || (__ballot(lanebad) != 0ull);
    float* dst = (type == 0) ? knnP : knnT;
    if (lane < KNN) dst[row * KNN + lane] = sqrtf(v);
    if (lane == 0) flags[type * NROWS + row] = bad ? 1u : 0u;
  } else {
    float a1[1] = {INFINITY};
    bool ovf = false;
    wave_grid_knn<1, 1>(2 * b + 1, e.x, e.y, e.z, sorted, pack, sS, sC, sP,
                        lane, a1, ovf);
    float v = a1[0];
#pragma unroll
    for (int s = 1; s < 64; s <<= 1) v = fminf(v, __shfl_xor(v, s, 64));
    if (lane == 0) mincol_arr[row] = sqrtf(v);
  }
}

// Guaranteed-exact dense fallback over one grid slice (8192 points):
// lane r (r<16) returns the r-th smallest squared distance.
__device__ float exact16_rowlist(const float4* __restrict__ base,
                                 float qx, float qy, float qz, int lane) {
  float a[KNN];
#pragma unroll
  for (int k = 0; k < KNN; ++k) a[k] = INFINITY;
  for (int s = 0; s < NPTS / 64; ++s) {
    float d = sqd3(qx, qy, qz, base[s * 64 + lane]);
    insertK(a, d);
  }
  float res = INFINITY;
#pragma unroll 1
  for (int r = 0; r < KNN; ++r) {
    float v = a[0];
    int idx = lane;
#pragma unroll
    for (int s = 1; s < 64; s <<= 1) {
      float ov = __shfl_xor(v, s, 64);
      int oi = __shfl_xor(idx, s, 64);
      bool take = (ov < v) || (ov == v && oi < idx);
      v = take ? ov : v;
      idx = take ? oi : idx;
    }
    if (lane == r) res = v;
    if (lane == idx) {
#pragma unroll
      for (int k = 0; k < KNN - 1; ++k) a[k] = a[k + 1];
      a[KNN - 1] = INFINITY;
    }
  }
  return res;
}

// Fix flagged rows exactly (expected ~0 per launch).
__global__ __launch_bounds__(256) void tail_kernel(
    const float* __restrict__ yt, const float4* __restrict__ sorted,
    const unsigned* __restrict__ flags,
    float* __restrict__ knnP, float* __restrict__ knnT) {
  const int lane = threadIdx.x & 63;
  const int wv = blockIdx.x * 4 + (threadIdx.x >> 6);   // 0..511
  const int base = wv * 64;                             // over 2*NROWS flags
  unsigned fl = flags[base + lane];
  unsigned long long mask = __ballot(fl != 0u);
  while (mask) {                                        // wave-uniform loop
    int rr = __ffsll(mask) - 1;
    mask &= mask - 1;
    int fid = base + rr;
    int type = fid >> 14;                               // NROWS == 1<<14
    int row = fid & (NROWS - 1);
    int b = row >> 13;
    int g = (type == 0) ? 2 * b : 2 * b + 1;
    const float* q = yt + 3 * row;
    float sres = exact16_rowlist(sorted + (size_t)g * NPTS, q[0], q[1], q[2], lane);
    float* dst = (type == 0) ? knnP : knnT;
    if (lane < KNN) dst[row * KNN + lane] = sqrtf(sres);
  }
}

// Per-block deterministic double partials: minrow (=knnP[.][0]), mincol, density.
__global__ __launch_bounds__(256) void combine_kernel(
    const float* __restrict__ knnP, const float* __restrict__ knnT,
    const float* __restrict__ mincol_arr, double* __restrict__ pd) {
  __shared__ double s1[256], s2[256], s3[256];
  const int t = threadIdx.x;
  const int row = blockIdx.x * 256 + t;
  float s = 0.0f;
#pragma unroll
  for (int k = 0; k < KNN; ++k)
    s += fabsf(knnP[row * KNN + k] - knnT[row * KNN + k]);
  s1[t] = (double)knnP[row * KNN];
  s2[t] = (double)mincol_arr[row];
  s3[t] = (double)s;
  __syncthreads();
  for (int off = 128; off > 0; off >>= 1) {
    if (t < off) { s1[t] += s1[t + off]; s2[t] += s2[t + off]; s3[t] += s3[t + off]; }
    __syncthreads();
  }
  if (t == 0) {
    pd[blockIdx.x * 3 + 0] = s1[0];
    pd[blockIdx.x * 3 + 1] = s2[0];
    pd[blockIdx.x * 3 + 2] = s3[0];
  }
}

__global__ __launch_bounds__(64) void finalize_kernel(
    const double* __restrict__ pd, float* __restrict__ out) {
  const int t = threadIdx.x;
  double a = pd[t * 3], b = pd[t * 3 + 1], c = pd[t * 3 + 2];
#pragma unroll
  for (int s = 32; s >= 1; s >>= 1) {
    a += __shfl_down(a, s, 64);
    b += __shfl_down(b, s, 64);
    c += __shfl_down(c, s, 64);
  }
  if (t == 0) {
    double shape = 0.5 * (a + b) / (double)NROWS;
    double dens = c / ((double)NROWS * KNN);
    out[0] = (float)(shape + dens);
    out[1] = (float)shape;
    out[2] = (float)dens;
  }
}

extern "C" void kernel_launch(void* const* d_in, const int* in_sizes, int n_in,
                              void* d_out, int out_size, void* d_ws, size_t ws_size,
                              hipStream_t stream) {
  (void)in_sizes; (void)n_in; (void)out_size; (void)ws_size;
  const float* yp = (const float*)d_in[0];  // y_pred [B, N, 3]
  const float* yt = (const float*)d_in[1];  // y_true [B, N, 3]
  char* w = (char*)d_ws;
  unsigned* counts  = (unsigned*)w;  w += TOTCELLS * 4;     // 512 KB
  unsigned* cursor  = (unsigned*)w;  w += TOTCELLS * 4;     // 512 KB (contig w/ counts)
  unsigned* partial = (unsigned*)w;  w += TOTCELLS * 4;
  unsigned* aux     = (unsigned*)w;  w += 512;
  unsigned* pack    = (unsigned*)w;  w += TOTCELLS * 4;
  float4*   sorted  = (float4*)w;    w += 2 * NROWS * 16;   // 1 MB
  float*    knnP    = (float*)w;     w += NROWS * KNN * 4;  // 1 MB
  float*    knnT    = (float*)w;     w += NROWS * KNN * 4;  // 1 MB
  float*    mincol  = (float*)w;     w += NROWS * 4;
  unsigned* flags   = (unsigned*)w;  w += 2 * NROWS * 4;    // written every launch
  double*   pd      = (double*)w;    w += 64 * 3 * 8;
  float* out = (float*)d_out;

  hipMemsetAsync(counts, 0, 2 * (size_t)TOTCELLS * 4, stream);  // counts+cursor
  count_kernel<<<2 * NROWS / 256, 256, 0, stream>>>(yp, yt, counts);
  scan1_kernel<<<SCAN_BLOCKS, 1024, 0, stream>>>(counts, partial, aux);
  scan2_kernel<<<1, SCAN_BLOCKS, 0, stream>>>(aux);
  pack_kernel<<<TOTCELLS / 1024, 1024, 0, stream>>>(counts, partial, aux, pack);
  scatter_kernel<<<2 * NROWS / 256, 256, 0, stream>>>(yp, yt, pack, cursor, sorted);
  query_kernel<<<3 * 16384 / 4, 256, 0, stream>>>(sorted, pack, knnP, knnT, mincol, flags);
  tail_kernel<<<2 * NROWS / 1024, 256, 0, stream>>>(yt, sorted, flags, knnP, knnT);
  combine_kernel<<<NROWS / 256, 256, 0, stream>>>(knnP, knnT, mincol, pd);
  finalize_kernel<<<1, 64, 0, stream>>>(pd, out);
}

// Round 10
// 146.777 us; speedup vs baseline: 9.0699x; 1.2333x over previous
//
#include <hip/hip_runtime.h>
#include <math.h>

#define NPTS 8192
#define NB 2
#define NROWS (NB * NPTS)
#define KNN 16
#define KC 6          // per-lane kept candidates (truncated sorted list)

// Spatial grid: 32^3 cells of width H. 4 grids: P/T x batch. g: P=2b, T=2b+1.
#define GRID 32
#define NCELLS (GRID * GRID * GRID)        // 32768
#define TOTCELLS (4 * NCELLS)              // 131072
#define H 0.35f
#define RLO (-5.6f)
#define INVH (1.0f / H)
#define SCAN_BLOCKS 128
#define SEGCAP 132                          // >= 2*64 segments per row-chunk

__device__ __forceinline__ int cellof(float x) {
  int c = (int)floorf((x - RLO) * INVH);
  return min(max(c, 0), GRID - 1);
}

__device__ __forceinline__ float sqd3(float qx, float qy, float qz, float4 c) {
  float dx = qx - c.x, dy = qy - c.y, dz = qz - c.z;
  return fmaf(dx, dx, fmaf(dy, dy, dz * dz));
}

__device__ __forceinline__ int lanerank(unsigned long long mk) {
  return __builtin_amdgcn_mbcnt_hi((unsigned)(mk >> 32),
                                   __builtin_amdgcn_mbcnt_lo((unsigned)mk, 0));
}

// Guarded insert into ascending sorted-K list (per-lane).
template <int K>
__device__ __forceinline__ void insertK(float (&a)[K], float d) {
  if (d < a[K - 1]) {
    a[K - 1] = d;
#pragma unroll
    for (int k = K - 1; k > 0; --k) {
      float lo = fminf(a[k - 1], a[k]);
      a[k] = fmaxf(a[k - 1], a[k]);
      a[k - 1] = lo;
    }
  }
}

// Full ascending bitonic sort of one value per lane across the 64-lane wave.
__device__ __forceinline__ float bitonic_sort64(float v, int lane) {
#pragma unroll
  for (int k = 2; k <= 64; k <<= 1) {
#pragma unroll
    for (int j = k >> 1; j >= 1; j >>= 1) {
      float o = __shfl_xor(v, j, 64);
      bool up = ((lane & k) == 0);
      bool lower = ((lane & j) == 0);
      float mn = fminf(v, o), mx = fmaxf(v, o);
      v = (up == lower) ? mn : mx;
    }
  }
  return v;
}

// Wave-cooperative kNN via expanding Chebyshev shells on a counting-sorted
// grid. After completing shell m, any unvisited point is at distance > m*H
// (0.999 slack covers float binning boundary error ~1e-7 << 3.4e-3 output
// threshold; clamped cells only increase true distances). Per-lane lists are
// truncated to K kept values; `dmin` tracks the minimum value ever evicted
// from this lane's list (evicted = max(d, a[K-1]) per insert; INF while the
// list isn't full). The caller uses dmin for an EXACT truncation-loss test.
// Stop when the wave has seen >= NEED candidates within the bound (counted
// from kept values only -- an undercount, so stopping is conservative).
template <int K, int NEED>
__device__ void wave_grid_knn(int g, float qx, float qy, float qz,
                              const float4* __restrict__ sorted,
                              const unsigned* __restrict__ pack,
                              unsigned* sStart, unsigned* sCnt, unsigned* sPre,
                              int lane, float (&a)[K], float& dmin) {
  const int cx = cellof(qx), cy = cellof(qy), cz = cellof(qz);
  const int base = g * NCELLS;
  for (int m = 0; m <= 34; ++m) {
    const int zlo = max(cz - m, 0), zhi = min(cz + m, GRID - 1);
    const int ylo = max(cy - m, 0), yhi = min(cy + m, GRID - 1);
    const int xlo = max(cx - m, 0), xhi = min(cx + m, GRID - 1);
    const int ny = yhi - ylo + 1;
    const int nrows = (zhi - zlo + 1) * ny;
    for (int rb = 0; rb < nrows; rb += 64) {
      const int rho = rb + lane;
      const bool act = rho < nrows;
      const int rr = act ? rho : 0;
      const int z = zlo + rr / ny, y = ylo + rr % ny;
      const int dza = abs(z - cz), dya = abs(y - cy);
      const bool bdry = (dza == m) || (dya == m);
      unsigned stA = 0, cnA = 0, stB = 0, cnB = 0;
      const int rowbase = base + (z * GRID + y) * GRID;
      if (act) {
        if (bdry) {  // full (clamped) x-range: contiguous segment, 2 loads
          unsigned plo = pack[rowbase + xlo];
          unsigned phi = pack[rowbase + xhi];
          stA = plo >> 14;
          cnA = ((phi >> 14) + (phi & 16383u)) - stA;
        } else {     // interior row: only the two new x = cx +- m cells
          int xl = cx - m, xr = cx + m;
          if (xl >= 0) { unsigned p = pack[rowbase + xl]; stA = p >> 14; cnA = p & 16383u; }
          if (xr < GRID) { unsigned p = pack[rowbase + xr]; stB = p >> 14; cnB = p & 16383u; }
        }
      }
      // ballot-compact nonempty segments into wave-private LDS
      unsigned long long mA = __ballot(cnA > 0);
      unsigned long long mB = __ballot(cnB > 0);
      int nA = __popcll(mA);
      int nseg = nA + __popcll(mB);
      if (nseg == 0) continue;
      int slA = lanerank(mA), slB = nA + lanerank(mB);
      if (cnA > 0) { sStart[slA] = stA; sCnt[slA] = cnA; }
      if (cnB > 0) { sStart[slB] = stB; sCnt[slB] = cnB; }
      // exclusive prefix over segment counts (<=128 segs, 2 halves of 64)
      unsigned total = 0;
      for (int h = 0; h < 2; ++h) {
        int sl = h * 64 + lane;
        unsigned v = (sl < nseg) ? sCnt[sl] : 0u;
        unsigned inc = v;
#pragma unroll
        for (int s2 = 1; s2 < 64; s2 <<= 1) {
          unsigned t = __shfl_up(inc, s2, 64);
          if (lane >= s2) inc += t;
        }
        if (sl < nseg) sPre[sl] = total + inc - v;
        total += __shfl(inc, 63, 64);
        if (nseg <= 64) break;
      }
      // candidates 64-wide across segment boundaries
      for (unsigned cb = 0; cb < total; cb += 64) {
        unsigned c = cb + (unsigned)lane;
        bool cact = c < total;
        unsigned cc = cact ? c : (total - 1);
        int lo = 0;  // max seg with sPre[seg] <= cc (sPre[0]==0)
#pragma unroll
        for (int sh = 64; sh >= 1; sh >>= 1) {
          int mid = lo + sh;
          if (mid < nseg && sPre[mid] <= cc) lo = mid;
        }
        float4 p = sorted[sStart[lo] + (cc - sPre[lo])];
        float d = cact ? sqd3(qx, qy, qz, p) : INFINITY;
        dmin = fminf(dmin, fmaxf(d, a[K - 1]));  // exact evicted-value track
        insertK(a, d);
      }
    }
    // stop test: >= NEED candidates within the provable bound?
    float bb = (float)m * (H * 0.999f);
    float bb2 = bb * bb;
    int cnt = 0;
#pragma unroll
    for (int k = 0; k < K; ++k) cnt += (a[k] <= bb2) ? 1 : 0;
#pragma unroll
    for (int s2 = 1; s2 < 64; s2 <<= 1) cnt += __shfl_xor(cnt, s2, 64);
    bool covered = (zlo == 0 && zhi == GRID - 1 && ylo == 0 &&
                    yhi == GRID - 1 && xlo == 0 && xhi == GRID - 1);
    if (cnt >= NEED || covered) break;
  }
}

// ---------- build ----------
__global__ __launch_bounds__(256) void count_kernel(
    const float* __restrict__ yp, const float* __restrict__ yt,
    unsigned* __restrict__ counts) {
  int t = blockIdx.x * 256 + threadIdx.x;          // 0 .. 2*NROWS-1
  const float* src;
  int g;
  if (t < NROWS) { src = yp + 3 * t; g = 2 * (t >> 13); }
  else { int u = t - NROWS; src = yt + 3 * u; g = 2 * (u >> 13) + 1; }
  atomicAdd(&counts[g * NCELLS + (cellof(src[2]) * GRID + cellof(src[1])) * GRID + cellof(src[0])], 1u);
}

__global__ __launch_bounds__(1024) void scan1_kernel(
    const unsigned* __restrict__ counts, unsigned* __restrict__ partial,
    unsigned* __restrict__ aux) {
  __shared__ unsigned s[1024];
  int t = threadIdx.x;
  int base = blockIdx.x * 1024;
  unsigned v = counts[base + t];
  s[t] = v;
  __syncthreads();
  for (int off = 1; off < 1024; off <<= 1) {
    unsigned add = (t >= off) ? s[t - off] : 0u;
    __syncthreads();
    s[t] += add;
    __syncthreads();
  }
  partial[base + t] = s[t] - v;
  if (t == 1023) aux[blockIdx.x] = s[t];
}

__global__ __launch_bounds__(SCAN_BLOCKS) void scan2_kernel(unsigned* __restrict__ aux) {
  __shared__ unsigned s[SCAN_BLOCKS];
  int t = threadIdx.x;
  unsigned v = aux[t];
  s[t] = v;
  __syncthreads();
  for (int off = 1; off < SCAN_BLOCKS; off <<= 1) {
    unsigned add = (t >= off) ? s[t - off] : 0u;
    __syncthreads();
    s[t] += add;
    __syncthreads();
  }
  aux[t] = s[t] - v;
}

// cellinfo pack: global start (<=18b) << 14 | count (14b)
__global__ __launch_bounds__(1024) void pack_kernel(
    const unsigned* __restrict__ counts, const unsigned* __restrict__ partial,
    const unsigned* __restrict__ aux, unsigned* __restrict__ pack) {
  int i = blockIdx.x * 1024 + threadIdx.x;
  unsigned start = partial[i] + aux[i >> 10];
  pack[i] = (start << 14) | counts[i];
}

__global__ __launch_bounds__(256) void scatter_kernel(
    const float* __restrict__ yp, const float* __restrict__ yt,
    const unsigned* __restrict__ pack, unsigned* __restrict__ cursor,
    float4* __restrict__ sorted) {
  int t = blockIdx.x * 256 + threadIdx.x;
  const float* src;
  int g, row;
  if (t < NROWS) { row = t; src = yp + 3 * t; g = 2 * (t >> 13); }
  else { row = t - NROWS; src = yt + 3 * row; g = 2 * (row >> 13) + 1; }
  float x = src[0], y = src[1], z = src[2];
  int flat = g * NCELLS + (cellof(z) * GRID + cellof(y)) * GRID + cellof(x);
  unsigned pos = (pack[flat] >> 14) + atomicAdd(&cursor[flat], 1u);
  sorted[pos] = make_float4(x, y, z, __int_as_float(row));
}

// ---------- queries: one wave per query, spatially-sorted order ----------
// wid [0,16384): T point vs P grid  -> knnP row (16 sqrt'd dists) + flag
// wid [16384,32768): T vs T grid    -> knnT row (self included) + flag
// wid [32768,49152): P vs T grid    -> mincol (exact, no flag)
__global__ __launch_bounds__(256) void query_kernel(
    const float4* __restrict__ sorted, const unsigned* __restrict__ pack,
    float* __restrict__ knnP, float* __restrict__ knnT,
    float* __restrict__ mincol_arr, unsigned* __restrict__ flags) {
  __shared__ unsigned sb[4][3][SEGCAP];
  __shared__ float cb[4][64];
  const int wave = threadIdx.x >> 6, lane = threadIdx.x & 63;
  const int wid = blockIdx.x * 4 + wave;
  const int type = wid >> 14;
  const int qid = wid & 16383;
  const int b = qid >> 13;
  const int src_g = (type == 2) ? 2 * b : 2 * b + 1;
  float4 e = sorted[src_g * NPTS + (qid & (NPTS - 1))];
  const int row = __float_as_int(e.w);
  unsigned* sS = sb[wave][0];
  unsigned* sC = sb[wave][1];
  unsigned* sP = sb[wave][2];
  float* cbuf = cb[wave];
  if (type < 2) {
    const int tgt_g = (type == 0) ? 2 * b : 2 * b + 1;
    float a[KC];
#pragma unroll
    for (int k = 0; k < KC; ++k) a[k] = INFINITY;
    float dmin = INFINITY;
    wave_grid_knn<KC, KNN>(tgt_g, e.x, e.y, e.z, sorted, pack, sS, sC, sP,
                           lane, a, dmin);
    // tau = 16th-smallest lane-min: >= 16 distinct candidates <= tau
    // (lane minima are never truncated away), and tau >= true 16th value.
    float slm = bitonic_sort64(a[0], lane);
    float tau = __shfl(slm, 15, 64);
    // compact all kept values <= tau, sort -> ascending top-16
    int tot = 0;
    int idx[KC];
#pragma unroll
    for (int k = 0; k < KC; ++k) {
      unsigned long long mk = __ballot(a[k] <= tau);
      idx[k] = tot + lanerank(mk);
      tot += __popcll(mk);
    }
#pragma unroll
    for (int k = 0; k < KC; ++k)
      if (a[k] <= tau && idx[k] < 64) cbuf[idx[k]] = a[k];
    float v = (lane < tot) ? cbuf[lane] : INFINITY;  // same-wave: no barrier
    v = bitonic_sort64(v, lane);
    float f15 = __shfl(v, 15, 64);
    // EXACT validity test: if any true top-16 member was evicted anywhere,
    // then dmin <= v16_true <= f15 (a subset's 16th order statistic can only
    // be >= the global one), so this flag provably catches every loss.
    bool bad = (tot > 64) || (__ballot(dmin <= f15) != 0ull);
    float* dst = (type == 0) ? knnP : knnT;
    if (lane < KNN) dst[row * KNN + lane] = sqrtf(v);
    if (lane == 0) flags[type * NROWS + row] = bad ? 1u : 0u;
  } else {
    float a1[1] = {INFINITY};
    float dmin = INFINITY;  // unused: lane minima are exact under truncation
    wave_grid_knn<1, 1>(2 * b + 1, e.x, e.y, e.z, sorted, pack, sS, sC, sP,
                        lane, a1, dmin);
    float v = a1[0];
#pragma unroll
    for (int s = 1; s < 64; s <<= 1) v = fminf(v, __shfl_xor(v, s, 64));
    if (lane == 0) mincol_arr[row] = sqrtf(v);
  }
}

// Guaranteed-exact dense fallback over one grid slice (8192 points):
// lane r (r<16) returns the r-th smallest squared distance.
__device__ float exact16_rowlist(const float4* __restrict__ base,
                                 float qx, float qy, float qz, int lane) {
  float a[KNN];
#pragma unroll
  for (int k = 0; k < KNN; ++k) a[k] = INFINITY;
  for (int s = 0; s < NPTS / 64; ++s) {
    float d = sqd3(qx, qy, qz, base[s * 64 + lane]);
    insertK(a, d);
  }
  float res = INFINITY;
#pragma unroll 1
  for (int r = 0; r < KNN; ++r) {
    float v = a[0];
    int idx = lane;
#pragma unroll
    for (int s = 1; s < 64; s <<= 1) {
      float ov = __shfl_xor(v, s, 64);
      int oi = __shfl_xor(idx, s, 64);
      bool take = (ov < v) || (ov == v && oi < idx);
      v = take ? ov : v;
      idx = take ? oi : idx;
    }
    if (lane == r) res = v;
    if (lane == idx) {
#pragma unroll
      for (int k = 0; k < KNN - 1; ++k) a[k] = a[k + 1];
      a[KNN - 1] = INFINITY;
    }
  }
  return res;
}

// Fix flagged rows exactly. Covers ALL 2*NROWS flags: 128 blocks x 4 waves
// x 64 flags = 32768. Expected flagged rows per launch: ~0.005 (exact flag
// needs one lane to hold >= 7 of a query's global top-16).
__global__ __launch_bounds__(256) void tail_kernel(
    const float* __restrict__ yt, const float4* __restrict__ sorted,
    const unsigned* __restrict__ flags,
    float* __restrict__ knnP, float* __restrict__ knnT) {
  const int lane = threadIdx.x & 63;
  const int wv = blockIdx.x * 4 + (threadIdx.x >> 6);   // 0..511
  const int base = wv * 64;                             // over 2*NROWS flags
  unsigned fl = flags[base + lane];
  unsigned long long mask = __ballot(fl != 0u);
  while (mask) {                                        // wave-uniform loop
    int rr = __ffsll(mask) - 1;
    mask &= mask - 1;
    int fid = base + rr;
    int type = fid >> 14;                               // NROWS == 1<<14
    int row = fid & (NROWS - 1);
    int b = row >> 13;
    int g = (type == 0) ? 2 * b : 2 * b + 1;
    const float* q = yt + 3 * row;
    float sres = exact16_rowlist(sorted + (size_t)g * NPTS, q[0], q[1], q[2], lane);
    float* dst = (type == 0) ? knnP : knnT;
    if (lane < KNN) dst[row * KNN + lane] = sqrtf(sres);
  }
}

// Per-block deterministic double partials: minrow (=knnP[.][0]), mincol, density.
__global__ __launch_bounds__(256) void combine_kernel(
    const float* __restrict__ knnP, const float* __restrict__ knnT,
    const float* __restrict__ mincol_arr, double* __restrict__ pd) {
  __shared__ double s1[256], s2[256], s3[256];
  const int t = threadIdx.x;
  const int row = blockIdx.x * 256 + t;
  float s = 0.0f;
#pragma unroll
  for (int k = 0; k < KNN; ++k)
    s += fabsf(knnP[row * KNN + k] - knnT[row * KNN + k]);
  s1[t] = (double)knnP[row * KNN];
  s2[t] = (double)mincol_arr[row];
  s3[t] = (double)s;
  __syncthreads();
  for (int off = 128; off > 0; off >>= 1) {
    if (t < off) { s1[t] += s1[t + off]; s2[t] += s2[t + off]; s3[t] += s3[t + off]; }
    __syncthreads();
  }
  if (t == 0) {
    pd[blockIdx.x * 3 + 0] = s1[0];
    pd[blockIdx.x * 3 + 1] = s2[0];
    pd[blockIdx.x * 3 + 2] = s3[0];
  }
}

__global__ __launch_bounds__(64) void finalize_kernel(
    const double* __restrict__ pd, float* __restrict__ out) {
  const int t = threadIdx.x;
  double a = pd[t * 3], b = pd[t * 3 + 1], c = pd[t * 3 + 2];
#pragma unroll
  for (int s = 32; s >= 1; s >>= 1) {
    a += __shfl_down(a, s, 64);
    b += __shfl_down(b, s, 64);
    c += __shfl_down(c, s, 64);
  }
  if (t == 0) {
    double shape = 0.5 * (a + b) / (double)NROWS;
    double dens = c / ((double)NROWS * KNN);
    out[0] = (float)(shape + dens);
    out[1] = (float)shape;
    out[2] = (float)dens;
  }
}

extern "C" void kernel_launch(void* const* d_in, const int* in_sizes, int n_in,
                              void* d_out, int out_size, void* d_ws, size_t ws_size,
                              hipStream_t stream) {
  (void)in_sizes; (void)n_in; (void)out_size; (void)ws_size;
  const float* yp = (const float*)d_in[0];  // y_pred [B, N, 3]
  const float* yt = (const float*)d_in[1];  // y_true [B, N, 3]
  char* w = (char*)d_ws;
  unsigned* counts  = (unsigned*)w;  w += TOTCELLS * 4;     // 512 KB
  unsigned* cursor  = (unsigned*)w;  w += TOTCELLS * 4;     // 512 KB (contig w/ counts)
  unsigned* partial = (unsigned*)w;  w += TOTCELLS * 4;
  unsigned* aux     = (unsigned*)w;  w += 512;
  unsigned* pack    = (unsigned*)w;  w += TOTCELLS * 4;
  float4*   sorted  = (float4*)w;    w += 2 * NROWS * 16;   // 1 MB
  float*    knnP    = (float*)w;     w += NROWS * KNN * 4;  // 1 MB
  float*    knnT    = (float*)w;     w += NROWS * KNN * 4;  // 1 MB
  float*    mincol  = (float*)w;     w += NROWS * 4;
  unsigned* flags   = (unsigned*)w;  w += 2 * NROWS * 4;    // written every launch
  double*   pd      = (double*)w;    w += 64 * 3 * 8;
  float* out = (float*)d_out;

  hipMemsetAsync(counts, 0, 2 * (size_t)TOTCELLS * 4, stream);  // counts+cursor
  count_kernel<<<2 * NROWS / 256, 256, 0, stream>>>(yp, yt, counts);
  scan1_kernel<<<SCAN_BLOCKS, 1024, 0, stream>>>(counts, partial, aux);
  scan2_kernel<<<1, SCAN_BLOCKS, 0, stream>>>(aux);
  pack_kernel<<<TOTCELLS / 1024, 1024, 0, stream>>>(counts, partial, aux, pack);
  scatter_kernel<<<2 * NROWS / 256, 256, 0, stream>>>(yp, yt, pack, cursor, sorted);
  query_kernel<<<3 * 16384 / 4, 256, 0, stream>>>(sorted, pack, knnP, knnT, mincol, flags);
  tail_kernel<<<2 * NROWS / 256, 256, 0, stream>>>(yt, sorted, flags, knnP, knnT);
  combine_kernel<<<NROWS / 256, 256, 0, stream>>>(knnP, knnT, mincol, pd);
  finalize_kernel<<<1, 64, 0, stream>>>(pd, out);
}